// Round 2
// baseline (2543.274 us; speedup 1.0000x reference)
//
#include <hip/hip_runtime.h>
#include <math.h>

// ---------------------------------------------------------------------------
// LowToHighMultiLevelReconstruction — round 2 (crash fix: ws 369MB -> 160MB,
// fused attention kernel, scatter folded into Wp-GEMM epilogue).
// ---------------------------------------------------------------------------

#define GS   128
#define WIN  256        // 2*GS
#define DQK  64
#define DV   64
#define DIMC 512
#define NTOK 8192

typedef unsigned long long u64;
typedef unsigned short u16;

__device__ __forceinline__ u16 f2b(float f) {     // f32 -> bf16 RNE
  unsigned u = __float_as_uint(f);
  u = (u + 0x7fffu + ((u >> 16) & 1u)) >> 16;
  return (u16)u;
}
__device__ __forceinline__ float b2f_lo(unsigned u) { return __uint_as_float(u << 16); }
__device__ __forceinline__ float b2f_hi(unsigned u) { return __uint_as_float(u & 0xffff0000u); }

__device__ __forceinline__ float wave_max64(float v) {
#pragma unroll
  for (int m = 1; m < 64; m <<= 1) v = fmaxf(v, __shfl_xor(v, m, 64));
  return v;
}
__device__ __forceinline__ float wave_sum64(float v) {
#pragma unroll
  for (int m = 1; m < 64; m <<= 1) v += __shfl_xor(v, m, 64);
  return v;
}

// ---------------------------------------------------------------- pooling ---
__global__ void pool_feat_kernel(const float* __restrict__ x,
                                 const float* __restrict__ scores,
                                 float* __restrict__ xl, float* __restrict__ sl,
                                 int n, int scale) {
  int npool = n / scale;
  int total = 2 * npool * (DIMC / 4);
  int tid = blockIdx.x * blockDim.x + threadIdx.x;
  if (tid >= total) return;
  int c4 = tid & 127;
  int g  = (tid >> 7) % npool;
  int b  = (tid >> 7) / npool;
  const float* xp = x + ((size_t)b * n + (size_t)g * scale) * DIMC + c4 * 4;
  float ax = 0.f, ay = 0.f, az = 0.f, aw = 0.f, wsum = 0.f, ssum = 0.f;
  for (int s = 0; s < scale; ++s) {
    float sc = scores[(size_t)b * n + (size_t)g * scale + s];
    float w  = fmaxf(sc, 1e-6f);
    float4 xv = *reinterpret_cast<const float4*>(xp + (size_t)s * DIMC);
    ax += xv.x * w; ay += xv.y * w; az += xv.z * w; aw += xv.w * w;
    wsum += w; ssum += sc;
  }
  float4 o = { ax / wsum, ay / wsum, az / wsum, aw / wsum };
  *reinterpret_cast<float4*>(xl + ((size_t)b * npool + g) * DIMC + c4 * 4) = o;
  if (c4 == 0) sl[(size_t)b * npool + g] = ssum / (float)scale;
}

__global__ void pool_label_kernel(const int* __restrict__ labels,
                                  const float* __restrict__ scores,
                                  int* __restrict__ ll, int n, int scale) {
  int npool = n / scale;
  int tid = blockIdx.x * blockDim.x + threadIdx.x;
  if (tid >= 2 * npool) return;
  int b = tid / npool, g = tid % npool;
  float counts[4] = {0.f, 0.f, 0.f, 0.f};
  float ssum[4]   = {0.f, 0.f, 0.f, 0.f};
  int firstp[4];
  for (int c = 0; c < 4; ++c) firstp[c] = scale;
  for (int s = 0; s < scale; ++s) {
    int   L = labels[(size_t)b * n + (size_t)g * scale + s];
    float S = scores[(size_t)b * n + (size_t)g * scale + s];
    counts[L] += 1.0f;
    ssum[L]   += S;
    if (s < firstp[L]) firstp[L] = s;
  }
  float cmax = fmaxf(fmaxf(counts[0], counts[1]), fmaxf(counts[2], counts[3]));
  float s2[4];
  for (int c = 0; c < 4; ++c) s2[c] = (counts[c] == cmax) ? ssum[c] : -1e9f;
  float smax = fmaxf(fmaxf(s2[0], s2[1]), fmaxf(s2[2], s2[3]));
  int fp[4];
  for (int c = 0; c < 4; ++c) fp[c] = (s2[c] == smax) ? firstp[c] : scale;
  int best = 0, bv = fp[0];
  for (int c = 1; c < 4; ++c) if (fp[c] < bv) { bv = fp[c]; best = c; }
  ll[(size_t)b * npool + g] = best;
}

// ------------------------------------------------------------ keep (focus) --
__global__ void keep_kernel(const int* __restrict__ ll, const float* __restrict__ sl,
                            int* __restrict__ keep, int total) {
  int tid = blockIdx.x * blockDim.x + threadIdx.x;
  if (tid >= total) return;
  const int*   lp = ll + (size_t)tid * GS;
  const float* sp = sl + (size_t)tid * GS;
  float counts[4] = {0.f, 0.f, 0.f, 0.f};
  for (int i = 0; i < GS; ++i) counts[lp[i]] += 1.f;
  int mode = 0; float bv = counts[0];
  for (int c = 1; c < 4; ++c) if (counts[c] > bv) { bv = counts[c]; mode = c; }
  float pm = 0.f, mean = 0.f;
  for (int i = 0; i < GS; ++i) { pm += (lp[i] == mode) ? 1.f : 0.f; mean += sp[i]; }
  float purity = pm / (float)GS;
  mean /= (float)GS;
  float var = 0.f;
  for (int i = 0; i < GS; ++i) { float d = sp[i] - mean; var += d * d; }
  var /= (float)GS;
  float focus = 0.5f + 0.25f * purity - 0.25f * var;
  focus = fminf(fmaxf(focus, 0.25f), 0.75f);
  keep[tid] = (int)ceilf(focus * (float)WIN);
}

// ----------------------------------------------------------------- SGEMM ----
// C = A(MxK) @ B(KxN).
// emode 0: f32 store to C. emode 1: bf16 store to Cb.
// emode 2: scatter-store to C via idx (rows expanded by scale). emode 3: += .
__global__ __launch_bounds__(256) void sgemm_kernel(
    const float* __restrict__ A, const float* __restrict__ B,
    float* __restrict__ C, u16* __restrict__ Cb, const int* __restrict__ idx,
    int M, int N, int K, int emode, int scale, int n_l) {
  __shared__ float As[16][128 + 4];
  __shared__ float Bs[16][128 + 4];
  int row0 = blockIdx.y * 128, col0 = blockIdx.x * 128;
  int tx = threadIdx.x & 15, ty = threadIdx.x >> 4;
  float acc[8][8] = {};
  for (int k0 = 0; k0 < K; k0 += 16) {
#pragma unroll
    for (int s = 0; s < 2; ++s) {
      int slot = threadIdx.x + s * 256;
      int ar = slot >> 2, ac = slot & 3;
      float4 av = *reinterpret_cast<const float4*>(A + (size_t)(row0 + ar) * K + k0 + ac * 4);
      As[ac * 4 + 0][ar] = av.x; As[ac * 4 + 1][ar] = av.y;
      As[ac * 4 + 2][ar] = av.z; As[ac * 4 + 3][ar] = av.w;
      int br = slot >> 5, bc = slot & 31;
      float4 bvv = *reinterpret_cast<const float4*>(B + (size_t)(k0 + br) * N + col0 + bc * 4);
      *reinterpret_cast<float4*>(&Bs[br][bc * 4]) = bvv;
    }
    __syncthreads();
#pragma unroll
    for (int kk = 0; kk < 16; ++kk) {
      float ra[8], rbv[8];
      *reinterpret_cast<float4*>(&ra[0]) = *reinterpret_cast<const float4*>(&As[kk][ty * 8]);
      *reinterpret_cast<float4*>(&ra[4]) = *reinterpret_cast<const float4*>(&As[kk][ty * 8 + 4]);
      *reinterpret_cast<float4*>(&rbv[0]) = *reinterpret_cast<const float4*>(&Bs[kk][tx * 8]);
      *reinterpret_cast<float4*>(&rbv[4]) = *reinterpret_cast<const float4*>(&Bs[kk][tx * 8 + 4]);
#pragma unroll
      for (int i = 0; i < 8; ++i)
#pragma unroll
        for (int j = 0; j < 8; ++j) acc[i][j] += ra[i] * rbv[j];
    }
    __syncthreads();
  }
  if (emode == 0) {
#pragma unroll
    for (int i = 0; i < 8; ++i) {
      float* crow = C + (size_t)(row0 + ty * 8 + i) * N + col0 + tx * 8;
      float4 v0 = { acc[i][0], acc[i][1], acc[i][2], acc[i][3] };
      float4 v1 = { acc[i][4], acc[i][5], acc[i][6], acc[i][7] };
      *reinterpret_cast<float4*>(crow) = v0;
      *reinterpret_cast<float4*>(crow + 4) = v1;
    }
  } else if (emode == 1) {
#pragma unroll
    for (int i = 0; i < 8; ++i) {
      uint4 ov;
      ov.x = (unsigned)f2b(acc[i][0]) | ((unsigned)f2b(acc[i][1]) << 16);
      ov.y = (unsigned)f2b(acc[i][2]) | ((unsigned)f2b(acc[i][3]) << 16);
      ov.z = (unsigned)f2b(acc[i][4]) | ((unsigned)f2b(acc[i][5]) << 16);
      ov.w = (unsigned)f2b(acc[i][6]) | ((unsigned)f2b(acc[i][7]) << 16);
      *reinterpret_cast<uint4*>(Cb + (size_t)(row0 + ty * 8 + i) * N + col0 + tx * 8) = ov;
    }
  } else {
#pragma unroll
    for (int i = 0; i < 8; ++i) {
      int r = row0 + ty * 8 + i;
      int bb = r / n_l, rr = r - bb * n_l;
      for (int s = 0; s < scale; ++s) {
        int dst = idx[(size_t)bb * NTOK + (size_t)rr * scale + s];
        float* p = C + ((size_t)bb * NTOK + dst) * N + col0 + tx * 8;
        if (emode == 3) {
          float4 o0 = *reinterpret_cast<float4*>(p);
          float4 o1 = *reinterpret_cast<float4*>(p + 4);
          o0.x += acc[i][0]; o0.y += acc[i][1]; o0.z += acc[i][2]; o0.w += acc[i][3];
          o1.x += acc[i][4]; o1.y += acc[i][5]; o1.z += acc[i][6]; o1.w += acc[i][7];
          *reinterpret_cast<float4*>(p) = o0;
          *reinterpret_cast<float4*>(p + 4) = o1;
        } else {
          float4 o0 = { acc[i][0], acc[i][1], acc[i][2], acc[i][3] };
          float4 o1 = { acc[i][4], acc[i][5], acc[i][6], acc[i][7] };
          *reinterpret_cast<float4*>(p) = o0;
          *reinterpret_cast<float4*>(p + 4) = o1;
        }
      }
    }
  }
}

// ----------------------------------------------- fused windowed attention ---
// One block (512 thr, 8 waves) per (b,g,h):
//   sim(128x256,f32 regs) -> exact stable top-k rank -> masked softmax ->
//   prior interp+mix -> attn bf16 (LDS + optional global) -> PV -> outp.
// LDS union: phase A {qT[64][132] f32, kT[64][260] f32} (100352 B)
//            phase B {aT[256][136] bf16, vsh[256][72] bf16} (106496 B)
//            + rbuf[8][256] u64 at 106496 (16384 B) -> 122880 B total.
__global__ __launch_bounds__(512) void attn_fused_kernel(
    const float* __restrict__ q, const float* __restrict__ k,
    const u16* __restrict__ vbf, const int* __restrict__ keepArr,
    const u16* __restrict__ prevA, u16* __restrict__ curA,
    const float* __restrict__ betaL, float* __restrict__ outp,
    int lvl, int n_l, int ng, int prev_ng) {
  __shared__ u64 smem8[15360];
  float* qT  = (float*)smem8;             // [64][132]
  float* kT  = qT + 64 * 132;             // [64][260]
  u16*   aT  = (u16*)smem8;               // [256][136]
  u16*   vsh = aT + 256 * 136;            // [256][72]
  u64*   rbuf = smem8 + (106496 / 8);     // [8][256]

  int t = threadIdx.x;
  int lane = t & 63, wave = t >> 6;
  int bid = blockIdx.x;
  int h = bid & 7;
  int g = (bid >> 3) % ng;
  int b = (bid >> 3) / ng;

  // ---- stage qT (transposed) ----
  const float* qbase = q + ((size_t)b * n_l + (size_t)g * GS) * DIMC + h * DQK;
#pragma unroll
  for (int it = 0; it < 4; ++it) {
    int idx = it * 512 + t;              // over 128*16
    int qi = idx >> 4, d4 = idx & 15;
    float4 vv = *reinterpret_cast<const float4*>(qbase + (size_t)qi * DIMC + d4 * 4);
    qT[(d4 * 4 + 0) * 132 + qi] = vv.x;
    qT[(d4 * 4 + 1) * 132 + qi] = vv.y;
    qT[(d4 * 4 + 2) * 132 + qi] = vv.z;
    qT[(d4 * 4 + 3) * 132 + qi] = vv.w;
  }
  // ---- stage kT (transposed, tail-reflected window) ----
  const float* kbase = k + (size_t)b * n_l * DIMC + h * DQK;
#pragma unroll
  for (int it = 0; it < 8; ++it) {
    int idx = it * 512 + t;              // over 256*16
    int j = idx >> 4, d4 = idx & 15;
    int p = g * GS + j;
    int src = (p < n_l) ? p : (2 * n_l - 1 - p);
    float4 vv = *reinterpret_cast<const float4*>(kbase + (size_t)src * DIMC + d4 * 4);
    kT[(d4 * 4 + 0) * 260 + j] = vv.x;
    kT[(d4 * 4 + 1) * 260 + j] = vv.y;
    kT[(d4 * 4 + 2) * 260 + j] = vv.z;
    kT[(d4 * 4 + 3) * 260 + j] = vv.w;
  }
  __syncthreads();

  // ---- sim: wave `wave` owns rows wave*16..+15; lane owns cols lane*4..+3 --
  float acc[16][4] = {};
#pragma unroll 2
  for (int d = 0; d < DQK; ++d) {
    float ra[16], rb4[4];
    *reinterpret_cast<float4*>(&ra[0])  = *reinterpret_cast<const float4*>(&qT[d * 132 + wave * 16 + 0]);
    *reinterpret_cast<float4*>(&ra[4])  = *reinterpret_cast<const float4*>(&qT[d * 132 + wave * 16 + 4]);
    *reinterpret_cast<float4*>(&ra[8])  = *reinterpret_cast<const float4*>(&qT[d * 132 + wave * 16 + 8]);
    *reinterpret_cast<float4*>(&ra[12]) = *reinterpret_cast<const float4*>(&qT[d * 132 + wave * 16 + 12]);
    *reinterpret_cast<float4*>(&rb4[0]) = *reinterpret_cast<const float4*>(&kT[d * 260 + lane * 4]);
#pragma unroll
    for (int i = 0; i < 16; ++i)
#pragma unroll
      for (int j = 0; j < 4; ++j) acc[i][j] += ra[i] * rb4[j];
  }
  __syncthreads();   // qT/kT dead from here

  // ---- stage vsh (bf16 V window) ----
  const u16* vbase = vbf + (size_t)b * n_l * DIMC + h * DV;
#pragma unroll
  for (int it = 0; it < 8; ++it) {
    int idx = it * 512 + t;              // over 256*16
    int j = idx >> 4, d4 = idx & 15;
    int p = g * GS + j;
    int src = (p < n_l) ? p : (2 * n_l - 1 - p);
    ushort4 vv = *reinterpret_cast<const ushort4*>(vbase + (size_t)src * DIMC + d4 * 4);
    *reinterpret_cast<ushort4*>(&vsh[j * 72 + d4 * 4]) = vv;
  }

  int kp = keepArr[b * ng + g];
  float beta = 0.f, wgt = 0.f;
  int lo = 0, hi = 0;
  if (lvl > 0) {
    beta = 1.f / (1.f + expf(-betaL[lvl]));
    float pos = ((float)g + 0.5f) * ((float)prev_ng / (float)ng) - 0.5f;
    float fl = floorf(pos);
    lo = (int)fl;
    if (lo < 0) lo = 0;
    if (lo > prev_ng - 1) lo = prev_ng - 1;
    hi = lo + 1; if (hi > prev_ng - 1) hi = prev_ng - 1;
    wgt = fminf(fmaxf(pos - fl, 0.f), 1.f);
  }

  // ---- per-row: rank -> mask -> softmax -> prior mix -> store attn ----
#pragma unroll
  for (int r = 0; r < 16; ++r) {
    int i = wave * 16 + r;
    float sv[4];
#pragma unroll
    for (int e = 0; e < 4; ++e) sv[e] = acc[r][e] * 0.125f;
    u64 key[4];
#pragma unroll
    for (int e = 0; e < 4; ++e) {
      unsigned u = __float_as_uint(sv[e]);
      u = (u & 0x80000000u) ? ~u : (u | 0x80000000u);
      int j = lane * 4 + e;
      key[e] = (((u64)u) << 8) | (u64)(255 - j);
    }
    __syncthreads();
    rbuf[wave * WIN + lane * 4 + 0] = key[0];
    rbuf[wave * WIN + lane * 4 + 1] = key[1];
    rbuf[wave * WIN + lane * 4 + 2] = key[2];
    rbuf[wave * WIN + lane * 4 + 3] = key[3];
    __syncthreads();
    int rk0 = 0, rk1 = 0, rk2 = 0, rk3 = 0;
#pragma unroll 8
    for (int j = 0; j < WIN; ++j) {
      u64 kj = rbuf[wave * WIN + j];
      rk0 += (kj > key[0]); rk1 += (kj > key[1]);
      rk2 += (kj > key[2]); rk3 += (kj > key[3]);
    }
    int rk[4] = { rk0, rk1, rk2, rk3 };
    bool msk[4];
    float m = -3.0e38f;
#pragma unroll
    for (int e = 0; e < 4; ++e) { msk[e] = rk[e] < kp; if (msk[e]) m = fmaxf(m, sv[e]); }
    m = wave_max64(m);
    float ez[4], zs = 0.f;
#pragma unroll
    for (int e = 0; e < 4; ++e) { ez[e] = msk[e] ? expf(sv[e] - m) : 0.f; zs += ez[e]; }
    zs = wave_sum64(zs);
    float at[4];
#pragma unroll
    for (int e = 0; e < 4; ++e) at[e] = ez[e] / zs;
    if (lvl > 0) {
      size_t baseLo = ((((size_t)b * prev_ng + lo) * 8 + h) * GS + i) * WIN + lane * 4;
      size_t baseHi = ((((size_t)b * prev_ng + hi) * 8 + h) * GS + i) * WIN + lane * 4;
      uint2 rlo = *reinterpret_cast<const uint2*>(prevA + baseLo);
      uint2 rhi = *reinterpret_cast<const uint2*>(prevA + baseHi);
      float pl[4] = { b2f_lo(rlo.x), b2f_hi(rlo.x), b2f_lo(rlo.y), b2f_hi(rlo.y) };
      float ph[4] = { b2f_lo(rhi.x), b2f_hi(rhi.x), b2f_lo(rhi.y), b2f_hi(rhi.y) };
      float pr[4], ps = 0.f;
#pragma unroll
      for (int e = 0; e < 4; ++e) {
        pr[e] = fmaxf((1.f - wgt) * pl[e] + wgt * ph[e], 0.f);
        ps += pr[e];
      }
      ps = wave_sum64(ps) + 1e-9f;
#pragma unroll
      for (int e = 0; e < 4; ++e) at[e] = (1.f - beta) * at[e] + beta * (pr[e] / ps);
    }
    u16 ab[4];
#pragma unroll
    for (int e = 0; e < 4; ++e) ab[e] = f2b(at[e]);
    aT[(lane * 4 + 0) * 136 + i] = ab[0];
    aT[(lane * 4 + 1) * 136 + i] = ab[1];
    aT[(lane * 4 + 2) * 136 + i] = ab[2];
    aT[(lane * 4 + 3) * 136 + i] = ab[3];
    if (curA != nullptr) {
      uint2 o;
      o.x = (unsigned)ab[0] | ((unsigned)ab[1] << 16);
      o.y = (unsigned)ab[2] | ((unsigned)ab[3] << 16);
      *reinterpret_cast<uint2*>(curA + ((size_t)bid * GS + i) * WIN + lane * 4) = o;
    }
  }
  __syncthreads();

  // ---- PV: out(128x64) = attn(128x256) @ V(256x64) ----
  int txp = t & 15, typ = t >> 4;        // 16 col-groups x 32 row-groups (of 4)
  float o2[4][4] = {};
#pragma unroll 4
  for (int j = 0; j < WIN; ++j) {
    uint2 a2 = *reinterpret_cast<const uint2*>(&aT[j * 136 + typ * 4]);
    uint2 v2 = *reinterpret_cast<const uint2*>(&vsh[j * 72 + txp * 4]);
    float pa[4]  = { b2f_lo(a2.x), b2f_hi(a2.x), b2f_lo(a2.y), b2f_hi(a2.y) };
    float pv4[4] = { b2f_lo(v2.x), b2f_hi(v2.x), b2f_lo(v2.y), b2f_hi(v2.y) };
#pragma unroll
    for (int ii = 0; ii < 4; ++ii)
#pragma unroll
      for (int jj = 0; jj < 4; ++jj) o2[ii][jj] += pa[ii] * pv4[jj];
  }
  float* obase = outp + ((size_t)b * n_l + (size_t)g * GS) * DIMC + h * DV;
#pragma unroll
  for (int ii = 0; ii < 4; ++ii) {
    float4 o = { o2[ii][0], o2[ii][1], o2[ii][2], o2[ii][3] };
    *reinterpret_cast<float4*>(&obase[(size_t)(typ * 4 + ii) * DIMC + txp * 4]) = o;
  }
}

// ---------------------------------------------------------------------------
extern "C" void kernel_launch(void* const* d_in, const int* in_sizes, int n_in,
                              void* d_out, int out_size, void* d_ws, size_t ws_size,
                              hipStream_t stream) {
  (void)in_sizes; (void)n_in; (void)out_size; (void)ws_size;
  const float* x        = (const float*)d_in[0];
  const int*   labels   = (const int*)d_in[1];
  const float* scores   = (const float*)d_in[2];
  const int*   idx_last = (const int*)d_in[3];
  const float* Wq       = (const float*)d_in[4];
  const float* Wk       = (const float*)d_in[5];
  const float* Wv       = (const float*)d_in[6];
  const float* Wp       = (const float*)d_in[7];
  const float* betaL    = (const float*)d_in[8];
  float* out = (float*)d_out;

  char* w = (char*)d_ws;
  size_t off = 0;
  auto take = [&](size_t bytes) -> char* {
    char* p = w + off;
    off += (bytes + 255) & ~(size_t)255;
    return p;
  };
  float* qb    = (float*)take(33554432);   // q f32 (max 2*8192*512)
  float* kb    = (float*)take(33554432);   // k f32
  u16*   vbf   = (u16*)  take(16777216);   // v bf16
  float* xo    = (float*)take(33554432);   // xl (pooled x) / outp union
  u16*   attnA = (u16*)  take(16777216);   // lvl0 attn bf16
  u16*   attnB = (u16*)  take(33554432);   // lvl1 attn bf16
  float* sl    = (float*)take(32768);
  int*   ll    = (int*)  take(32768);
  int*   keepb = (int*)  take(1024);
  // total ~160.07 MB

  const size_t wstride = (size_t)DIMC * DIMC;
  for (int lvl = 0; lvl < 3; ++lvl) {
    int scale = (lvl == 0) ? 4 : (lvl == 1) ? 2 : 1;
    int n_l = NTOK / scale;
    int ng  = n_l / GS;
    int M   = 2 * n_l;
    const float* xin; const int* lin; const float* sin_;
    if (scale > 1) {
      int tfeat = 2 * n_l * (DIMC / 4);
      pool_feat_kernel<<<(tfeat + 255) / 256, 256, 0, stream>>>(x, scores, xo, sl, NTOK, scale);
      pool_label_kernel<<<(2 * n_l + 255) / 256, 256, 0, stream>>>(labels, scores, ll, NTOK, scale);
      xin = xo; lin = ll; sin_ = sl;
    } else {
      xin = x; lin = labels; sin_ = scores;
    }
    keep_kernel<<<(2 * ng + 127) / 128, 128, 0, stream>>>(lin, sin_, keepb, 2 * ng);

    dim3 gg(DIMC / 128, M / 128);
    sgemm_kernel<<<gg, 256, 0, stream>>>(xin, Wq + lvl * wstride, qb, nullptr, nullptr,
                                         M, DIMC, DIMC, 0, 0, 0);
    sgemm_kernel<<<gg, 256, 0, stream>>>(xin, Wk + lvl * wstride, kb, nullptr, nullptr,
                                         M, DIMC, DIMC, 0, 0, 0);
    sgemm_kernel<<<gg, 256, 0, stream>>>(xin, Wv + lvl * wstride, nullptr, vbf, nullptr,
                                         M, DIMC, DIMC, 1, 0, 0);

    const u16* prev = (lvl == 0) ? nullptr : ((lvl == 1) ? attnA : attnB);
    u16* cur = (lvl == 0) ? attnA : ((lvl == 1) ? attnB : nullptr);
    attn_fused_kernel<<<2 * ng * 8, 512, 0, stream>>>(qb, kb, vbf, keepb, prev, cur,
                                                      betaL, xo, lvl, n_l, ng, ng / 2);

    sgemm_kernel<<<gg, 256, 0, stream>>>(xo, Wp + lvl * wstride, out, nullptr, idx_last,
                                         M, DIMC, DIMC, (lvl == 0) ? 2 : 3, scale, n_l);
  }
}

// Round 3
// 1634.252 us; speedup vs baseline: 1.5562x; 1.5562x over previous
//
#include <hip/hip_runtime.h>
#include <math.h>

// ---------------------------------------------------------------------------
// LowToHighMultiLevelReconstruction — round 3.
// Change vs round 2: exact top-k mask via wave-ballot binary search (32-step
// bit-build on monotone u32) instead of O(WIN^2) u64 rank compares in LDS.
// Removes 32 barriers/block + rbuf (LDS 122880 -> 106496 B). Mask provably
// identical to stable-descending-rank < keep.
// ---------------------------------------------------------------------------

#define GS   128
#define WIN  256        // 2*GS
#define DQK  64
#define DV   64
#define DIMC 512
#define NTOK 8192

typedef unsigned long long u64;
typedef unsigned short u16;

__device__ __forceinline__ u16 f2b(float f) {     // f32 -> bf16 RNE
  unsigned u = __float_as_uint(f);
  u = (u + 0x7fffu + ((u >> 16) & 1u)) >> 16;
  return (u16)u;
}
__device__ __forceinline__ float b2f_lo(unsigned u) { return __uint_as_float(u << 16); }
__device__ __forceinline__ float b2f_hi(unsigned u) { return __uint_as_float(u & 0xffff0000u); }

__device__ __forceinline__ float wave_max64(float v) {
#pragma unroll
  for (int m = 1; m < 64; m <<= 1) v = fmaxf(v, __shfl_xor(v, m, 64));
  return v;
}
__device__ __forceinline__ float wave_sum64(float v) {
#pragma unroll
  for (int m = 1; m < 64; m <<= 1) v += __shfl_xor(v, m, 64);
  return v;
}

// ---------------------------------------------------------------- pooling ---
__global__ void pool_feat_kernel(const float* __restrict__ x,
                                 const float* __restrict__ scores,
                                 float* __restrict__ xl, float* __restrict__ sl,
                                 int n, int scale) {
  int npool = n / scale;
  int total = 2 * npool * (DIMC / 4);
  int tid = blockIdx.x * blockDim.x + threadIdx.x;
  if (tid >= total) return;
  int c4 = tid & 127;
  int g  = (tid >> 7) % npool;
  int b  = (tid >> 7) / npool;
  const float* xp = x + ((size_t)b * n + (size_t)g * scale) * DIMC + c4 * 4;
  float ax = 0.f, ay = 0.f, az = 0.f, aw = 0.f, wsum = 0.f, ssum = 0.f;
  for (int s = 0; s < scale; ++s) {
    float sc = scores[(size_t)b * n + (size_t)g * scale + s];
    float w  = fmaxf(sc, 1e-6f);
    float4 xv = *reinterpret_cast<const float4*>(xp + (size_t)s * DIMC);
    ax += xv.x * w; ay += xv.y * w; az += xv.z * w; aw += xv.w * w;
    wsum += w; ssum += sc;
  }
  float4 o = { ax / wsum, ay / wsum, az / wsum, aw / wsum };
  *reinterpret_cast<float4*>(xl + ((size_t)b * npool + g) * DIMC + c4 * 4) = o;
  if (c4 == 0) sl[(size_t)b * npool + g] = ssum / (float)scale;
}

__global__ void pool_label_kernel(const int* __restrict__ labels,
                                  const float* __restrict__ scores,
                                  int* __restrict__ ll, int n, int scale) {
  int npool = n / scale;
  int tid = blockIdx.x * blockDim.x + threadIdx.x;
  if (tid >= 2 * npool) return;
  int b = tid / npool, g = tid % npool;
  float counts[4] = {0.f, 0.f, 0.f, 0.f};
  float ssum[4]   = {0.f, 0.f, 0.f, 0.f};
  int firstp[4];
  for (int c = 0; c < 4; ++c) firstp[c] = scale;
  for (int s = 0; s < scale; ++s) {
    int   L = labels[(size_t)b * n + (size_t)g * scale + s];
    float S = scores[(size_t)b * n + (size_t)g * scale + s];
    counts[L] += 1.0f;
    ssum[L]   += S;
    if (s < firstp[L]) firstp[L] = s;
  }
  float cmax = fmaxf(fmaxf(counts[0], counts[1]), fmaxf(counts[2], counts[3]));
  float s2[4];
  for (int c = 0; c < 4; ++c) s2[c] = (counts[c] == cmax) ? ssum[c] : -1e9f;
  float smax = fmaxf(fmaxf(s2[0], s2[1]), fmaxf(s2[2], s2[3]));
  int fp[4];
  for (int c = 0; c < 4; ++c) fp[c] = (s2[c] == smax) ? firstp[c] : scale;
  int best = 0, bv = fp[0];
  for (int c = 1; c < 4; ++c) if (fp[c] < bv) { bv = fp[c]; best = c; }
  ll[(size_t)b * npool + g] = best;
}

// ------------------------------------------------------------ keep (focus) --
__global__ void keep_kernel(const int* __restrict__ ll, const float* __restrict__ sl,
                            int* __restrict__ keep, int total) {
  int tid = blockIdx.x * blockDim.x + threadIdx.x;
  if (tid >= total) return;
  const int*   lp = ll + (size_t)tid * GS;
  const float* sp = sl + (size_t)tid * GS;
  float counts[4] = {0.f, 0.f, 0.f, 0.f};
  for (int i = 0; i < GS; ++i) counts[lp[i]] += 1.f;
  int mode = 0; float bv = counts[0];
  for (int c = 1; c < 4; ++c) if (counts[c] > bv) { bv = counts[c]; mode = c; }
  float pm = 0.f, mean = 0.f;
  for (int i = 0; i < GS; ++i) { pm += (lp[i] == mode) ? 1.f : 0.f; mean += sp[i]; }
  float purity = pm / (float)GS;
  mean /= (float)GS;
  float var = 0.f;
  for (int i = 0; i < GS; ++i) { float d = sp[i] - mean; var += d * d; }
  var /= (float)GS;
  float focus = 0.5f + 0.25f * purity - 0.25f * var;
  focus = fminf(fmaxf(focus, 0.25f), 0.75f);
  keep[tid] = (int)ceilf(focus * (float)WIN);
}

// ----------------------------------------------------------------- SGEMM ----
// C = A(MxK) @ B(KxN).
// emode 0: f32 store to C. emode 1: bf16 store to Cb.
// emode 2: scatter-store to C via idx (rows expanded by scale). emode 3: += .
__global__ __launch_bounds__(256) void sgemm_kernel(
    const float* __restrict__ A, const float* __restrict__ B,
    float* __restrict__ C, u16* __restrict__ Cb, const int* __restrict__ idx,
    int M, int N, int K, int emode, int scale, int n_l) {
  __shared__ float As[16][128 + 4];
  __shared__ float Bs[16][128 + 4];
  int row0 = blockIdx.y * 128, col0 = blockIdx.x * 128;
  int tx = threadIdx.x & 15, ty = threadIdx.x >> 4;
  float acc[8][8] = {};
  for (int k0 = 0; k0 < K; k0 += 16) {
#pragma unroll
    for (int s = 0; s < 2; ++s) {
      int slot = threadIdx.x + s * 256;
      int ar = slot >> 2, ac = slot & 3;
      float4 av = *reinterpret_cast<const float4*>(A + (size_t)(row0 + ar) * K + k0 + ac * 4);
      As[ac * 4 + 0][ar] = av.x; As[ac * 4 + 1][ar] = av.y;
      As[ac * 4 + 2][ar] = av.z; As[ac * 4 + 3][ar] = av.w;
      int br = slot >> 5, bc = slot & 31;
      float4 bvv = *reinterpret_cast<const float4*>(B + (size_t)(k0 + br) * N + col0 + bc * 4);
      *reinterpret_cast<float4*>(&Bs[br][bc * 4]) = bvv;
    }
    __syncthreads();
#pragma unroll
    for (int kk = 0; kk < 16; ++kk) {
      float ra[8], rbv[8];
      *reinterpret_cast<float4*>(&ra[0]) = *reinterpret_cast<const float4*>(&As[kk][ty * 8]);
      *reinterpret_cast<float4*>(&ra[4]) = *reinterpret_cast<const float4*>(&As[kk][ty * 8 + 4]);
      *reinterpret_cast<float4*>(&rbv[0]) = *reinterpret_cast<const float4*>(&Bs[kk][tx * 8]);
      *reinterpret_cast<float4*>(&rbv[4]) = *reinterpret_cast<const float4*>(&Bs[kk][tx * 8 + 4]);
#pragma unroll
      for (int i = 0; i < 8; ++i)
#pragma unroll
        for (int j = 0; j < 8; ++j) acc[i][j] += ra[i] * rbv[j];
    }
    __syncthreads();
  }
  if (emode == 0) {
#pragma unroll
    for (int i = 0; i < 8; ++i) {
      float* crow = C + (size_t)(row0 + ty * 8 + i) * N + col0 + tx * 8;
      float4 v0 = { acc[i][0], acc[i][1], acc[i][2], acc[i][3] };
      float4 v1 = { acc[i][4], acc[i][5], acc[i][6], acc[i][7] };
      *reinterpret_cast<float4*>(crow) = v0;
      *reinterpret_cast<float4*>(crow + 4) = v1;
    }
  } else if (emode == 1) {
#pragma unroll
    for (int i = 0; i < 8; ++i) {
      uint4 ov;
      ov.x = (unsigned)f2b(acc[i][0]) | ((unsigned)f2b(acc[i][1]) << 16);
      ov.y = (unsigned)f2b(acc[i][2]) | ((unsigned)f2b(acc[i][3]) << 16);
      ov.z = (unsigned)f2b(acc[i][4]) | ((unsigned)f2b(acc[i][5]) << 16);
      ov.w = (unsigned)f2b(acc[i][6]) | ((unsigned)f2b(acc[i][7]) << 16);
      *reinterpret_cast<uint4*>(Cb + (size_t)(row0 + ty * 8 + i) * N + col0 + tx * 8) = ov;
    }
  } else {
#pragma unroll
    for (int i = 0; i < 8; ++i) {
      int r = row0 + ty * 8 + i;
      int bb = r / n_l, rr = r - bb * n_l;
      for (int s = 0; s < scale; ++s) {
        int dst = idx[(size_t)bb * NTOK + (size_t)rr * scale + s];
        float* p = C + ((size_t)bb * NTOK + dst) * N + col0 + tx * 8;
        if (emode == 3) {
          float4 o0 = *reinterpret_cast<float4*>(p);
          float4 o1 = *reinterpret_cast<float4*>(p + 4);
          o0.x += acc[i][0]; o0.y += acc[i][1]; o0.z += acc[i][2]; o0.w += acc[i][3];
          o1.x += acc[i][4]; o1.y += acc[i][5]; o1.z += acc[i][6]; o1.w += acc[i][7];
          *reinterpret_cast<float4*>(p) = o0;
          *reinterpret_cast<float4*>(p + 4) = o1;
        } else {
          float4 o0 = { acc[i][0], acc[i][1], acc[i][2], acc[i][3] };
          float4 o1 = { acc[i][4], acc[i][5], acc[i][6], acc[i][7] };
          *reinterpret_cast<float4*>(p) = o0;
          *reinterpret_cast<float4*>(p + 4) = o1;
        }
      }
    }
  }
}

// ----------------------------------------------- fused windowed attention ---
// One block (512 thr, 8 waves) per (b,g,h):
//   sim(128x256,f32 regs) -> ballot-select exact top-k mask -> masked softmax
//   -> prior interp+mix -> attn bf16 (LDS + optional global) -> PV -> outp.
// LDS union: phase A {qT[64][132] f32, kT[64][260] f32} (100352 B)
//            phase B {aT[256][136] bf16, vsh[256][72] bf16} (106496 B)
__global__ __launch_bounds__(512) void attn_fused_kernel(
    const float* __restrict__ q, const float* __restrict__ k,
    const u16* __restrict__ vbf, const int* __restrict__ keepArr,
    const u16* __restrict__ prevA, u16* __restrict__ curA,
    const float* __restrict__ betaL, float* __restrict__ outp,
    int lvl, int n_l, int ng, int prev_ng) {
  __shared__ u64 smem8[13312];
  float* qT  = (float*)smem8;             // [64][132]
  float* kT  = qT + 64 * 132;             // [64][260]
  u16*   aT  = (u16*)smem8;               // [256][136]
  u16*   vsh = aT + 256 * 136;            // [256][72]

  int t = threadIdx.x;
  int lane = t & 63, wave = t >> 6;
  int bid = blockIdx.x;
  int h = bid & 7;
  int g = (bid >> 3) % ng;
  int b = (bid >> 3) / ng;

  // ---- stage qT (transposed) ----
  const float* qbase = q + ((size_t)b * n_l + (size_t)g * GS) * DIMC + h * DQK;
#pragma unroll
  for (int it = 0; it < 4; ++it) {
    int idx = it * 512 + t;              // over 128*16
    int qi = idx >> 4, d4 = idx & 15;
    float4 vv = *reinterpret_cast<const float4*>(qbase + (size_t)qi * DIMC + d4 * 4);
    qT[(d4 * 4 + 0) * 132 + qi] = vv.x;
    qT[(d4 * 4 + 1) * 132 + qi] = vv.y;
    qT[(d4 * 4 + 2) * 132 + qi] = vv.z;
    qT[(d4 * 4 + 3) * 132 + qi] = vv.w;
  }
  // ---- stage kT (transposed, tail-reflected window) ----
  const float* kbase = k + (size_t)b * n_l * DIMC + h * DQK;
#pragma unroll
  for (int it = 0; it < 8; ++it) {
    int idx = it * 512 + t;              // over 256*16
    int j = idx >> 4, d4 = idx & 15;
    int p = g * GS + j;
    int src = (p < n_l) ? p : (2 * n_l - 1 - p);
    float4 vv = *reinterpret_cast<const float4*>(kbase + (size_t)src * DIMC + d4 * 4);
    kT[(d4 * 4 + 0) * 260 + j] = vv.x;
    kT[(d4 * 4 + 1) * 260 + j] = vv.y;
    kT[(d4 * 4 + 2) * 260 + j] = vv.z;
    kT[(d4 * 4 + 3) * 260 + j] = vv.w;
  }
  __syncthreads();

  // ---- sim: wave `wave` owns rows wave*16..+15; lane owns cols lane*4..+3 --
  float acc[16][4] = {};
#pragma unroll 2
  for (int d = 0; d < DQK; ++d) {
    float ra[16], rb4[4];
    *reinterpret_cast<float4*>(&ra[0])  = *reinterpret_cast<const float4*>(&qT[d * 132 + wave * 16 + 0]);
    *reinterpret_cast<float4*>(&ra[4])  = *reinterpret_cast<const float4*>(&qT[d * 132 + wave * 16 + 4]);
    *reinterpret_cast<float4*>(&ra[8])  = *reinterpret_cast<const float4*>(&qT[d * 132 + wave * 16 + 8]);
    *reinterpret_cast<float4*>(&ra[12]) = *reinterpret_cast<const float4*>(&qT[d * 132 + wave * 16 + 12]);
    *reinterpret_cast<float4*>(&rb4[0]) = *reinterpret_cast<const float4*>(&kT[d * 260 + lane * 4]);
#pragma unroll
    for (int i = 0; i < 16; ++i)
#pragma unroll
      for (int j = 0; j < 4; ++j) acc[i][j] += ra[i] * rb4[j];
  }
  __syncthreads();   // qT/kT dead from here

  // ---- stage vsh (bf16 V window) ----
  const u16* vbase = vbf + (size_t)b * n_l * DIMC + h * DV;
#pragma unroll
  for (int it = 0; it < 8; ++it) {
    int idx = it * 512 + t;              // over 256*16
    int j = idx >> 4, d4 = idx & 15;
    int p = g * GS + j;
    int src = (p < n_l) ? p : (2 * n_l - 1 - p);
    ushort4 vv = *reinterpret_cast<const ushort4*>(vbase + (size_t)src * DIMC + d4 * 4);
    *reinterpret_cast<ushort4*>(&vsh[j * 72 + d4 * 4]) = vv;
  }

  int kp = keepArr[b * ng + g];
  float beta = 0.f, wgt = 0.f;
  int lo = 0, hi = 0;
  if (lvl > 0) {
    beta = 1.f / (1.f + expf(-betaL[lvl]));
    float pos = ((float)g + 0.5f) * ((float)prev_ng / (float)ng) - 0.5f;
    float fl = floorf(pos);
    lo = (int)fl;
    if (lo < 0) lo = 0;
    if (lo > prev_ng - 1) lo = prev_ng - 1;
    hi = lo + 1; if (hi > prev_ng - 1) hi = prev_ng - 1;
    wgt = fminf(fmaxf(pos - fl, 0.f), 1.f);
  }
  u64 lmask = (1ull << lane) - 1ull;     // lanes strictly below mine

  // ---- per-row: ballot top-k select -> softmax -> prior mix -> store ----
#pragma unroll
  for (int r = 0; r < 16; ++r) {
    int i = wave * 16 + r;
    float sv[4];
    unsigned um[4];
#pragma unroll
    for (int e = 0; e < 4; ++e) {
      sv[e] = acc[r][e] * 0.125f;
      unsigned u = __float_as_uint(sv[e]);
      um[e] = (u & 0x80000000u) ? ~u : (u | 0x80000000u);
    }
    // T = kp-th largest monotone-u32 value (exact), MSB-first bit build.
    unsigned T = 0u;
    for (int bit = 31; bit >= 0; --bit) {
      unsigned T2 = T | (1u << bit);
      int c = __popcll(__ballot(um[0] >= T2)) + __popcll(__ballot(um[1] >= T2))
            + __popcll(__ballot(um[2] >= T2)) + __popcll(__ballot(um[3] >= T2));
      if (c >= kp) T = T2;
    }
    int c_gt = __popcll(__ballot(um[0] > T)) + __popcll(__ballot(um[1] > T))
             + __popcll(__ballot(um[2] > T)) + __popcll(__ballot(um[3] > T));
    u64 beq[4];
#pragma unroll
    for (int e = 0; e < 4; ++e) beq[e] = __ballot(um[e] == T);
    int trbase = __popcll(beq[0] & lmask) + __popcll(beq[1] & lmask)
               + __popcll(beq[2] & lmask) + __popcll(beq[3] & lmask);
    int need = kp - c_gt;                 // ties admitted, ascending index
    bool msk[4];
    int own = 0;
#pragma unroll
    for (int e = 0; e < 4; ++e) {
      bool eq = (um[e] == T);
      msk[e] = (um[e] > T) || (eq && (trbase + own) < need);
      own += eq ? 1 : 0;
    }
    float m = -3.0e38f;
#pragma unroll
    for (int e = 0; e < 4; ++e) if (msk[e]) m = fmaxf(m, sv[e]);
    m = wave_max64(m);
    float ez[4], zs = 0.f;
#pragma unroll
    for (int e = 0; e < 4; ++e) { ez[e] = msk[e] ? __expf(sv[e] - m) : 0.f; zs += ez[e]; }
    zs = wave_sum64(zs);
    float at[4];
#pragma unroll
    for (int e = 0; e < 4; ++e) at[e] = ez[e] / zs;
    if (lvl > 0) {
      size_t baseLo = ((((size_t)b * prev_ng + lo) * 8 + h) * GS + i) * WIN + lane * 4;
      size_t baseHi = ((((size_t)b * prev_ng + hi) * 8 + h) * GS + i) * WIN + lane * 4;
      uint2 rlo = *reinterpret_cast<const uint2*>(prevA + baseLo);
      uint2 rhi = *reinterpret_cast<const uint2*>(prevA + baseHi);
      float pl[4] = { b2f_lo(rlo.x), b2f_hi(rlo.x), b2f_lo(rlo.y), b2f_hi(rlo.y) };
      float ph[4] = { b2f_lo(rhi.x), b2f_hi(rhi.x), b2f_lo(rhi.y), b2f_hi(rhi.y) };
      float pr[4], ps = 0.f;
#pragma unroll
      for (int e = 0; e < 4; ++e) {
        pr[e] = fmaxf((1.f - wgt) * pl[e] + wgt * ph[e], 0.f);
        ps += pr[e];
      }
      ps = wave_sum64(ps) + 1e-9f;
#pragma unroll
      for (int e = 0; e < 4; ++e) at[e] = (1.f - beta) * at[e] + beta * (pr[e] / ps);
    }
    u16 ab[4];
#pragma unroll
    for (int e = 0; e < 4; ++e) ab[e] = f2b(at[e]);
    aT[(lane * 4 + 0) * 136 + i] = ab[0];
    aT[(lane * 4 + 1) * 136 + i] = ab[1];
    aT[(lane * 4 + 2) * 136 + i] = ab[2];
    aT[(lane * 4 + 3) * 136 + i] = ab[3];
    if (curA != nullptr) {
      uint2 o;
      o.x = (unsigned)ab[0] | ((unsigned)ab[1] << 16);
      o.y = (unsigned)ab[2] | ((unsigned)ab[3] << 16);
      *reinterpret_cast<uint2*>(curA + ((size_t)bid * GS + i) * WIN + lane * 4) = o;
    }
  }
  __syncthreads();

  // ---- PV: out(128x64) = attn(128x256) @ V(256x64) ----
  int txp = t & 15, typ = t >> 4;        // 16 col-groups x 32 row-groups (of 4)
  float o2[4][4] = {};
#pragma unroll 4
  for (int j = 0; j < WIN; ++j) {
    uint2 a2 = *reinterpret_cast<const uint2*>(&aT[j * 136 + typ * 4]);
    uint2 v2 = *reinterpret_cast<const uint2*>(&vsh[j * 72 + txp * 4]);
    float pa[4]  = { b2f_lo(a2.x), b2f_hi(a2.x), b2f_lo(a2.y), b2f_hi(a2.y) };
    float pv4[4] = { b2f_lo(v2.x), b2f_hi(v2.x), b2f_lo(v2.y), b2f_hi(v2.y) };
#pragma unroll
    for (int ii = 0; ii < 4; ++ii)
#pragma unroll
      for (int jj = 0; jj < 4; ++jj) o2[ii][jj] += pa[ii] * pv4[jj];
  }
  float* obase = outp + ((size_t)b * n_l + (size_t)g * GS) * DIMC + h * DV;
#pragma unroll
  for (int ii = 0; ii < 4; ++ii) {
    float4 o = { o2[ii][0], o2[ii][1], o2[ii][2], o2[ii][3] };
    *reinterpret_cast<float4*>(&obase[(size_t)(typ * 4 + ii) * DIMC + txp * 4]) = o;
  }
}

// ---------------------------------------------------------------------------
extern "C" void kernel_launch(void* const* d_in, const int* in_sizes, int n_in,
                              void* d_out, int out_size, void* d_ws, size_t ws_size,
                              hipStream_t stream) {
  (void)in_sizes; (void)n_in; (void)out_size; (void)ws_size;
  const float* x        = (const float*)d_in[0];
  const int*   labels   = (const int*)d_in[1];
  const float* scores   = (const float*)d_in[2];
  const int*   idx_last = (const int*)d_in[3];
  const float* Wq       = (const float*)d_in[4];
  const float* Wk       = (const float*)d_in[5];
  const float* Wv       = (const float*)d_in[6];
  const float* Wp       = (const float*)d_in[7];
  const float* betaL    = (const float*)d_in[8];
  float* out = (float*)d_out;

  char* w = (char*)d_ws;
  size_t off = 0;
  auto take = [&](size_t bytes) -> char* {
    char* p = w + off;
    off += (bytes + 255) & ~(size_t)255;
    return p;
  };
  float* qb    = (float*)take(33554432);   // q f32 (max 2*8192*512)
  float* kb    = (float*)take(33554432);   // k f32
  u16*   vbf   = (u16*)  take(16777216);   // v bf16
  float* xo    = (float*)take(33554432);   // xl (pooled x) / outp union
  u16*   attnA = (u16*)  take(16777216);   // lvl0 attn bf16
  u16*   attnB = (u16*)  take(33554432);   // lvl1 attn bf16
  float* sl    = (float*)take(32768);
  int*   ll    = (int*)  take(32768);
  int*   keepb = (int*)  take(1024);
  // total ~160.07 MB

  const size_t wstride = (size_t)DIMC * DIMC;
  for (int lvl = 0; lvl < 3; ++lvl) {
    int scale = (lvl == 0) ? 4 : (lvl == 1) ? 2 : 1;
    int n_l = NTOK / scale;
    int ng  = n_l / GS;
    int M   = 2 * n_l;
    const float* xin; const int* lin; const float* sin_;
    if (scale > 1) {
      int tfeat = 2 * n_l * (DIMC / 4);
      pool_feat_kernel<<<(tfeat + 255) / 256, 256, 0, stream>>>(x, scores, xo, sl, NTOK, scale);
      pool_label_kernel<<<(2 * n_l + 255) / 256, 256, 0, stream>>>(labels, scores, ll, NTOK, scale);
      xin = xo; lin = ll; sin_ = sl;
    } else {
      xin = x; lin = labels; sin_ = scores;
    }
    keep_kernel<<<(2 * ng + 127) / 128, 128, 0, stream>>>(lin, sin_, keepb, 2 * ng);

    dim3 gg(DIMC / 128, M / 128);
    sgemm_kernel<<<gg, 256, 0, stream>>>(xin, Wq + lvl * wstride, qb, nullptr, nullptr,
                                         M, DIMC, DIMC, 0, 0, 0);
    sgemm_kernel<<<gg, 256, 0, stream>>>(xin, Wk + lvl * wstride, kb, nullptr, nullptr,
                                         M, DIMC, DIMC, 0, 0, 0);
    sgemm_kernel<<<gg, 256, 0, stream>>>(xin, Wv + lvl * wstride, nullptr, vbf, nullptr,
                                         M, DIMC, DIMC, 1, 0, 0);

    const u16* prev = (lvl == 0) ? nullptr : ((lvl == 1) ? attnA : attnB);
    u16* cur = (lvl == 0) ? attnA : ((lvl == 1) ? attnB : nullptr);
    attn_fused_kernel<<<2 * ng * 8, 512, 0, stream>>>(qb, kb, vbf, keepb, prev, cur,
                                                      betaL, xo, lvl, n_l, ng, ng / 2);

    sgemm_kernel<<<gg, 256, 0, stream>>>(xo, Wp + lvl * wstride, out, nullptr, idx_last,
                                         M, DIMC, DIMC, (lvl == 0) ? 2 : 3, scale, n_l);
  }
}

// Round 4
// 1060.896 us; speedup vs baseline: 2.3973x; 1.5404x over previous
//
#include <hip/hip_runtime.h>
#include <math.h>

// ---------------------------------------------------------------------------
// LowToHighMultiLevelReconstruction — round 4.
// Change vs round 3: all four projection GEMMs moved from f32 VALU to
// bf16-split MFMA (16x16x32). q/k use 3-product split (hi*hi+hi*lo+lo*hi,
// ~f32 accuracy -> exact top-k preserved); V and Wp use hi-only.
// A-side split happens during LDS staging (f32 -> hi/lo bf16); weights are
// pre-transposed+split by wsplitT_kernel. Attention kernel unchanged.
// ---------------------------------------------------------------------------

#define GS   128
#define WIN  256        // 2*GS
#define DQK  64
#define DV   64
#define DIMC 512
#define NTOK 8192

typedef unsigned long long u64;
typedef unsigned short u16;
typedef __attribute__((ext_vector_type(8))) short bf16x8;
typedef __attribute__((ext_vector_type(4))) float f32x4;

__device__ __forceinline__ u16 f2b(float f) {     // f32 -> bf16 RNE
  unsigned u = __float_as_uint(f);
  u = (u + 0x7fffu + ((u >> 16) & 1u)) >> 16;
  return (u16)u;
}
__device__ __forceinline__ float b2f(u16 h) { return __uint_as_float(((unsigned)h) << 16); }
__device__ __forceinline__ float b2f_lo(unsigned u) { return __uint_as_float(u << 16); }
__device__ __forceinline__ float b2f_hi(unsigned u) { return __uint_as_float(u & 0xffff0000u); }

__device__ __forceinline__ float wave_max64(float v) {
#pragma unroll
  for (int m = 1; m < 64; m <<= 1) v = fmaxf(v, __shfl_xor(v, m, 64));
  return v;
}
__device__ __forceinline__ float wave_sum64(float v) {
#pragma unroll
  for (int m = 1; m < 64; m <<= 1) v += __shfl_xor(v, m, 64);
  return v;
}

// ---------------------------------------------------------------- pooling ---
__global__ void pool_feat_kernel(const float* __restrict__ x,
                                 const float* __restrict__ scores,
                                 float* __restrict__ xl, float* __restrict__ sl,
                                 int n, int scale) {
  int npool = n / scale;
  int total = 2 * npool * (DIMC / 4);
  int tid = blockIdx.x * blockDim.x + threadIdx.x;
  if (tid >= total) return;
  int c4 = tid & 127;
  int g  = (tid >> 7) % npool;
  int b  = (tid >> 7) / npool;
  const float* xp = x + ((size_t)b * n + (size_t)g * scale) * DIMC + c4 * 4;
  float ax = 0.f, ay = 0.f, az = 0.f, aw = 0.f, wsum = 0.f, ssum = 0.f;
  for (int s = 0; s < scale; ++s) {
    float sc = scores[(size_t)b * n + (size_t)g * scale + s];
    float w  = fmaxf(sc, 1e-6f);
    float4 xv = *reinterpret_cast<const float4*>(xp + (size_t)s * DIMC);
    ax += xv.x * w; ay += xv.y * w; az += xv.z * w; aw += xv.w * w;
    wsum += w; ssum += sc;
  }
  float4 o = { ax / wsum, ay / wsum, az / wsum, aw / wsum };
  *reinterpret_cast<float4*>(xl + ((size_t)b * npool + g) * DIMC + c4 * 4) = o;
  if (c4 == 0) sl[(size_t)b * npool + g] = ssum / (float)scale;
}

__global__ void pool_label_kernel(const int* __restrict__ labels,
                                  const float* __restrict__ scores,
                                  int* __restrict__ ll, int n, int scale) {
  int npool = n / scale;
  int tid = blockIdx.x * blockDim.x + threadIdx.x;
  if (tid >= 2 * npool) return;
  int b = tid / npool, g = tid % npool;
  float counts[4] = {0.f, 0.f, 0.f, 0.f};
  float ssum[4]   = {0.f, 0.f, 0.f, 0.f};
  int firstp[4];
  for (int c = 0; c < 4; ++c) firstp[c] = scale;
  for (int s = 0; s < scale; ++s) {
    int   L = labels[(size_t)b * n + (size_t)g * scale + s];
    float S = scores[(size_t)b * n + (size_t)g * scale + s];
    counts[L] += 1.0f;
    ssum[L]   += S;
    if (s < firstp[L]) firstp[L] = s;
  }
  float cmax = fmaxf(fmaxf(counts[0], counts[1]), fmaxf(counts[2], counts[3]));
  float s2[4];
  for (int c = 0; c < 4; ++c) s2[c] = (counts[c] == cmax) ? ssum[c] : -1e9f;
  float smax = fmaxf(fmaxf(s2[0], s2[1]), fmaxf(s2[2], s2[3]));
  int fp[4];
  for (int c = 0; c < 4; ++c) fp[c] = (s2[c] == smax) ? firstp[c] : scale;
  int best = 0, bv = fp[0];
  for (int c = 1; c < 4; ++c) if (fp[c] < bv) { bv = fp[c]; best = c; }
  ll[(size_t)b * npool + g] = best;
}

// ------------------------------------------------------------ keep (focus) --
__global__ void keep_kernel(const int* __restrict__ ll, const float* __restrict__ sl,
                            int* __restrict__ keep, int total) {
  int tid = blockIdx.x * blockDim.x + threadIdx.x;
  if (tid >= total) return;
  const int*   lp = ll + (size_t)tid * GS;
  const float* sp = sl + (size_t)tid * GS;
  float counts[4] = {0.f, 0.f, 0.f, 0.f};
  for (int i = 0; i < GS; ++i) counts[lp[i]] += 1.f;
  int mode = 0; float bv = counts[0];
  for (int c = 1; c < 4; ++c) if (counts[c] > bv) { bv = counts[c]; mode = c; }
  float pm = 0.f, mean = 0.f;
  for (int i = 0; i < GS; ++i) { pm += (lp[i] == mode) ? 1.f : 0.f; mean += sp[i]; }
  float purity = pm / (float)GS;
  mean /= (float)GS;
  float var = 0.f;
  for (int i = 0; i < GS; ++i) { float d = sp[i] - mean; var += d * d; }
  var /= (float)GS;
  float focus = 0.5f + 0.25f * purity - 0.25f * var;
  focus = fminf(fmaxf(focus, 0.25f), 0.75f);
  keep[tid] = (int)ceilf(focus * (float)WIN);
}

// ------------------------------------------- weight transpose + bf16 split --
// W f32 [512][512] (k,n) -> Bt hi/lo bf16 [512][512] (n,k). lo may be null.
__global__ __launch_bounds__(256) void wsplitT_kernel(const float* __restrict__ W,
                                                      u16* __restrict__ bthi,
                                                      u16* __restrict__ btlo) {
  __shared__ float tile[32][33];
  int bx = blockIdx.x & 15;        // n block
  int by = blockIdx.x >> 4;        // k block
  int tx = threadIdx.x & 31;
  int ty = threadIdx.x >> 5;       // 0..7
#pragma unroll
  for (int i = 0; i < 4; ++i) {
    int kk = ty + i * 8;
    tile[kk][tx] = W[(size_t)(by * 32 + kk) * 512 + bx * 32 + tx];
  }
  __syncthreads();
#pragma unroll
  for (int i = 0; i < 4; ++i) {
    int nn = ty + i * 8;
    float v = tile[tx][nn];        // = W[by*32+tx][bx*32+nn]
    u16 h = f2b(v);
    size_t o = (size_t)(bx * 32 + nn) * 512 + by * 32 + tx;
    bthi[o] = h;
    if (btlo) btlo[o] = f2b(v - b2f(h));
  }
}

// ------------------------------------------------------- MFMA split GEMM ----
// C(MxN=512) = A(Mx512 f32) @ W(512x512), K=N=512.
// A is split f32->bf16 hi/lo during staging. B (Bthi/Btlo) pre-transposed
// [n][k] bf16. SPLIT=1: 3-product split (q,k). SPLIT=0: hi-only (v, wp).
// EMODE 0: f32 store C. 1: bf16 store Cb. 2: scatter via idx (scale rows).
// 3: scatter +=.
template<int SPLIT, int EMODE>
__global__ __launch_bounds__(256) void mgemm_kernel(
    const float* __restrict__ Af,
    const u16* __restrict__ Bthi, const u16* __restrict__ Btlo,
    float* __restrict__ C, u16* __restrict__ Cb, const int* __restrict__ idx,
    int M, int scale, int n_l) {
  __shared__ u16 smem[SPLIT ? 4 * 5120 : 2 * 5120];   // [128][40] tiles
  u16* sAhi = smem;
  u16* sBhi = smem + 5120;
  u16* sAlo = SPLIT ? smem + 2 * 5120 : smem;
  u16* sBlo = SPLIT ? smem + 3 * 5120 : smem;

  int t = threadIdx.x, lane = t & 63, wave = t >> 6;
  int wr = wave >> 1, wc = wave & 1;
  int row0 = blockIdx.y * 128, col0 = blockIdx.x * 128;

  const f32x4 zero = { 0.f, 0.f, 0.f, 0.f };
  f32x4 acc[4][4];
#pragma unroll
  for (int i = 0; i < 4; ++i)
#pragma unroll
    for (int j = 0; j < 4; ++j) acc[i][j] = zero;

  for (int k0 = 0; k0 < 512; k0 += 32) {
    // ---- stage A (f32 -> hi/lo bf16): 128x32 tile, 1024 float4 chunks ----
#pragma unroll
    for (int it = 0; it < 4; ++it) {
      int c = it * 256 + t;
      int r = c >> 3, s = c & 7;
      float4 v = *reinterpret_cast<const float4*>(Af + (size_t)(row0 + r) * 512 + k0 + s * 4);
      ushort4 h, l;
      h.x = f2b(v.x); h.y = f2b(v.y); h.z = f2b(v.z); h.w = f2b(v.w);
      *reinterpret_cast<ushort4*>(&sAhi[r * 40 + s * 4]) = h;
      if (SPLIT) {
        l.x = f2b(v.x - b2f(h.x)); l.y = f2b(v.y - b2f(h.y));
        l.z = f2b(v.z - b2f(h.z)); l.w = f2b(v.w - b2f(h.w));
        *reinterpret_cast<ushort4*>(&sAlo[r * 40 + s * 4]) = l;
      }
    }
    // ---- stage B (bf16, pre-transposed): 128x32 tile, 512 uint4 chunks ----
#pragma unroll
    for (int it = 0; it < 2; ++it) {
      int c = it * 256 + t;
      int r = c >> 2, s = c & 3;
      uint4 vb = *reinterpret_cast<const uint4*>(Bthi + (size_t)(col0 + r) * 512 + k0 + s * 8);
      *reinterpret_cast<uint4*>(&sBhi[r * 40 + s * 8]) = vb;
      if (SPLIT) {
        uint4 vl = *reinterpret_cast<const uint4*>(Btlo + (size_t)(col0 + r) * 512 + k0 + s * 8);
        *reinterpret_cast<uint4*>(&sBlo[r * 40 + s * 8]) = vl;
      }
    }
    __syncthreads();

    int fr = lane & 15;            // row/col within fragment
    int kf = (lane >> 4) * 8;      // k offset within fragment
    bf16x8 ah[4], bh[4], al[4], bl[4];
#pragma unroll
    for (int i = 0; i < 4; ++i) {
      ah[i] = *reinterpret_cast<const bf16x8*>(&sAhi[(wr * 64 + i * 16 + fr) * 40 + kf]);
      bh[i] = *reinterpret_cast<const bf16x8*>(&sBhi[(wc * 64 + i * 16 + fr) * 40 + kf]);
      if (SPLIT) {
        al[i] = *reinterpret_cast<const bf16x8*>(&sAlo[(wr * 64 + i * 16 + fr) * 40 + kf]);
        bl[i] = *reinterpret_cast<const bf16x8*>(&sBlo[(wc * 64 + i * 16 + fr) * 40 + kf]);
      }
    }
#pragma unroll
    for (int i = 0; i < 4; ++i)
#pragma unroll
      for (int j = 0; j < 4; ++j) {
        acc[i][j] = __builtin_amdgcn_mfma_f32_16x16x32_bf16(ah[i], bh[j], acc[i][j], 0, 0, 0);
        if (SPLIT) {
          acc[i][j] = __builtin_amdgcn_mfma_f32_16x16x32_bf16(ah[i], bl[j], acc[i][j], 0, 0, 0);
          acc[i][j] = __builtin_amdgcn_mfma_f32_16x16x32_bf16(al[i], bh[j], acc[i][j], 0, 0, 0);
        }
      }
    __syncthreads();
  }

  // ---- epilogue ----
  int ccol = col0 + wc * 64 + (lane & 15);
  int crow = row0 + wr * 64 + (lane >> 4) * 4;
#pragma unroll
  for (int i = 0; i < 4; ++i) {
#pragma unroll
    for (int r = 0; r < 4; ++r) {
      int gr = crow + i * 16 + r;
      if (EMODE == 0) {
#pragma unroll
        for (int j = 0; j < 4; ++j)
          C[(size_t)gr * 512 + ccol + j * 16] = acc[i][j][r];
      } else if (EMODE == 1) {
#pragma unroll
        for (int j = 0; j < 4; ++j)
          Cb[(size_t)gr * 512 + ccol + j * 16] = f2b(acc[i][j][r]);
      } else {
        int bb = gr / n_l, rr = gr - bb * n_l;
        for (int s = 0; s < scale; ++s) {
          int dst = idx[(size_t)bb * NTOK + (size_t)rr * scale + s];
          float* p = C + ((size_t)bb * NTOK + dst) * 512 + ccol;
          if (EMODE == 3) {
#pragma unroll
            for (int j = 0; j < 4; ++j) p[j * 16] += acc[i][j][r];
          } else {
#pragma unroll
            for (int j = 0; j < 4; ++j) p[j * 16] = acc[i][j][r];
          }
        }
      }
    }
  }
}

// ----------------------------------------------- fused windowed attention ---
// One block (512 thr, 8 waves) per (b,g,h):
//   sim(128x256,f32 regs) -> ballot-select exact top-k mask -> masked softmax
//   -> prior interp+mix -> attn bf16 (LDS + optional global) -> PV -> outp.
__global__ __launch_bounds__(512) void attn_fused_kernel(
    const float* __restrict__ q, const float* __restrict__ k,
    const u16* __restrict__ vbf, const int* __restrict__ keepArr,
    const u16* __restrict__ prevA, u16* __restrict__ curA,
    const float* __restrict__ betaL, float* __restrict__ outp,
    int lvl, int n_l, int ng, int prev_ng) {
  __shared__ u64 smem8[13312];
  float* qT  = (float*)smem8;             // [64][132]
  float* kT  = qT + 64 * 132;             // [64][260]
  u16*   aT  = (u16*)smem8;               // [256][136]
  u16*   vsh = aT + 256 * 136;            // [256][72]

  int t = threadIdx.x;
  int lane = t & 63, wave = t >> 6;
  int bid = blockIdx.x;
  int h = bid & 7;
  int g = (bid >> 3) % ng;
  int b = (bid >> 3) / ng;

  const float* qbase = q + ((size_t)b * n_l + (size_t)g * GS) * DIMC + h * DQK;
#pragma unroll
  for (int it = 0; it < 4; ++it) {
    int idx = it * 512 + t;              // over 128*16
    int qi = idx >> 4, d4 = idx & 15;
    float4 vv = *reinterpret_cast<const float4*>(qbase + (size_t)qi * DIMC + d4 * 4);
    qT[(d4 * 4 + 0) * 132 + qi] = vv.x;
    qT[(d4 * 4 + 1) * 132 + qi] = vv.y;
    qT[(d4 * 4 + 2) * 132 + qi] = vv.z;
    qT[(d4 * 4 + 3) * 132 + qi] = vv.w;
  }
  const float* kbase = k + (size_t)b * n_l * DIMC + h * DQK;
#pragma unroll
  for (int it = 0; it < 8; ++it) {
    int idx = it * 512 + t;              // over 256*16
    int j = idx >> 4, d4 = idx & 15;
    int p = g * GS + j;
    int src = (p < n_l) ? p : (2 * n_l - 1 - p);
    float4 vv = *reinterpret_cast<const float4*>(kbase + (size_t)src * DIMC + d4 * 4);
    kT[(d4 * 4 + 0) * 260 + j] = vv.x;
    kT[(d4 * 4 + 1) * 260 + j] = vv.y;
    kT[(d4 * 4 + 2) * 260 + j] = vv.z;
    kT[(d4 * 4 + 3) * 260 + j] = vv.w;
  }
  __syncthreads();

  float acc[16][4] = {};
#pragma unroll 2
  for (int d = 0; d < DQK; ++d) {
    float ra[16], rb4[4];
    *reinterpret_cast<float4*>(&ra[0])  = *reinterpret_cast<const float4*>(&qT[d * 132 + wave * 16 + 0]);
    *reinterpret_cast<float4*>(&ra[4])  = *reinterpret_cast<const float4*>(&qT[d * 132 + wave * 16 + 4]);
    *reinterpret_cast<float4*>(&ra[8])  = *reinterpret_cast<const float4*>(&qT[d * 132 + wave * 16 + 8]);
    *reinterpret_cast<float4*>(&ra[12]) = *reinterpret_cast<const float4*>(&qT[d * 132 + wave * 16 + 12]);
    *reinterpret_cast<float4*>(&rb4[0]) = *reinterpret_cast<const float4*>(&kT[d * 260 + lane * 4]);
#pragma unroll
    for (int i = 0; i < 16; ++i)
#pragma unroll
      for (int j = 0; j < 4; ++j) acc[i][j] += ra[i] * rb4[j];
  }
  __syncthreads();   // qT/kT dead from here

  const u16* vbase = vbf + (size_t)b * n_l * DIMC + h * DV;
#pragma unroll
  for (int it = 0; it < 8; ++it) {
    int idx = it * 512 + t;              // over 256*16
    int j = idx >> 4, d4 = idx & 15;
    int p = g * GS + j;
    int src = (p < n_l) ? p : (2 * n_l - 1 - p);
    ushort4 vv = *reinterpret_cast<const ushort4*>(vbase + (size_t)src * DIMC + d4 * 4);
    *reinterpret_cast<ushort4*>(&vsh[j * 72 + d4 * 4]) = vv;
  }

  int kp = keepArr[b * ng + g];
  float beta = 0.f, wgt = 0.f;
  int lo = 0, hi = 0;
  if (lvl > 0) {
    beta = 1.f / (1.f + expf(-betaL[lvl]));
    float pos = ((float)g + 0.5f) * ((float)prev_ng / (float)ng) - 0.5f;
    float fl = floorf(pos);
    lo = (int)fl;
    if (lo < 0) lo = 0;
    if (lo > prev_ng - 1) lo = prev_ng - 1;
    hi = lo + 1; if (hi > prev_ng - 1) hi = prev_ng - 1;
    wgt = fminf(fmaxf(pos - fl, 0.f), 1.f);
  }
  u64 lmask = (1ull << lane) - 1ull;

#pragma unroll
  for (int r = 0; r < 16; ++r) {
    int i = wave * 16 + r;
    float sv[4];
    unsigned um[4];
#pragma unroll
    for (int e = 0; e < 4; ++e) {
      sv[e] = acc[r][e] * 0.125f;
      unsigned u = __float_as_uint(sv[e]);
      um[e] = (u & 0x80000000u) ? ~u : (u | 0x80000000u);
    }
    unsigned T = 0u;
    for (int bit = 31; bit >= 0; --bit) {
      unsigned T2 = T | (1u << bit);
      int c = __popcll(__ballot(um[0] >= T2)) + __popcll(__ballot(um[1] >= T2))
            + __popcll(__ballot(um[2] >= T2)) + __popcll(__ballot(um[3] >= T2));
      if (c >= kp) T = T2;
    }
    int c_gt = __popcll(__ballot(um[0] > T)) + __popcll(__ballot(um[1] > T))
             + __popcll(__ballot(um[2] > T)) + __popcll(__ballot(um[3] > T));
    u64 beq[4];
#pragma unroll
    for (int e = 0; e < 4; ++e) beq[e] = __ballot(um[e] == T);
    int trbase = __popcll(beq[0] & lmask) + __popcll(beq[1] & lmask)
               + __popcll(beq[2] & lmask) + __popcll(beq[3] & lmask);
    int need = kp - c_gt;
    bool msk[4];
    int own = 0;
#pragma unroll
    for (int e = 0; e < 4; ++e) {
      bool eq = (um[e] == T);
      msk[e] = (um[e] > T) || (eq && (trbase + own) < need);
      own += eq ? 1 : 0;
    }
    float m = -3.0e38f;
#pragma unroll
    for (int e = 0; e < 4; ++e) if (msk[e]) m = fmaxf(m, sv[e]);
    m = wave_max64(m);
    float ez[4], zs = 0.f;
#pragma unroll
    for (int e = 0; e < 4; ++e) { ez[e] = msk[e] ? __expf(sv[e] - m) : 0.f; zs += ez[e]; }
    zs = wave_sum64(zs);
    float at[4];
#pragma unroll
    for (int e = 0; e < 4; ++e) at[e] = ez[e] / zs;
    if (lvl > 0) {
      size_t baseLo = ((((size_t)b * prev_ng + lo) * 8 + h) * GS + i) * WIN + lane * 4;
      size_t baseHi = ((((size_t)b * prev_ng + hi) * 8 + h) * GS + i) * WIN + lane * 4;
      uint2 rlo = *reinterpret_cast<const uint2*>(prevA + baseLo);
      uint2 rhi = *reinterpret_cast<const uint2*>(prevA + baseHi);
      float pl[4] = { b2f_lo(rlo.x), b2f_hi(rlo.x), b2f_lo(rlo.y), b2f_hi(rlo.y) };
      float ph[4] = { b2f_lo(rhi.x), b2f_hi(rhi.x), b2f_lo(rhi.y), b2f_hi(rhi.y) };
      float pr[4], ps = 0.f;
#pragma unroll
      for (int e = 0; e < 4; ++e) {
        pr[e] = fmaxf((1.f - wgt) * pl[e] + wgt * ph[e], 0.f);
        ps += pr[e];
      }
      ps = wave_sum64(ps) + 1e-9f;
#pragma unroll
      for (int e = 0; e < 4; ++e) at[e] = (1.f - beta) * at[e] + beta * (pr[e] / ps);
    }
    u16 ab[4];
#pragma unroll
    for (int e = 0; e < 4; ++e) ab[e] = f2b(at[e]);
    aT[(lane * 4 + 0) * 136 + i] = ab[0];
    aT[(lane * 4 + 1) * 136 + i] = ab[1];
    aT[(lane * 4 + 2) * 136 + i] = ab[2];
    aT[(lane * 4 + 3) * 136 + i] = ab[3];
    if (curA != nullptr) {
      uint2 o;
      o.x = (unsigned)ab[0] | ((unsigned)ab[1] << 16);
      o.y = (unsigned)ab[2] | ((unsigned)ab[3] << 16);
      *reinterpret_cast<uint2*>(curA + ((size_t)bid * GS + i) * WIN + lane * 4) = o;
    }
  }
  __syncthreads();

  int txp = t & 15, typ = t >> 4;
  float o2[4][4] = {};
#pragma unroll 4
  for (int j = 0; j < WIN; ++j) {
    uint2 a2 = *reinterpret_cast<const uint2*>(&aT[j * 136 + typ * 4]);
    uint2 v2 = *reinterpret_cast<const uint2*>(&vsh[j * 72 + txp * 4]);
    float pa[4]  = { b2f_lo(a2.x), b2f_hi(a2.x), b2f_lo(a2.y), b2f_hi(a2.y) };
    float pv4[4] = { b2f_lo(v2.x), b2f_hi(v2.x), b2f_lo(v2.y), b2f_hi(v2.y) };
#pragma unroll
    for (int ii = 0; ii < 4; ++ii)
#pragma unroll
      for (int jj = 0; jj < 4; ++jj) o2[ii][jj] += pa[ii] * pv4[jj];
  }
  float* obase = outp + ((size_t)b * n_l + (size_t)g * GS) * DIMC + h * DV;
#pragma unroll
  for (int ii = 0; ii < 4; ++ii) {
    float4 o = { o2[ii][0], o2[ii][1], o2[ii][2], o2[ii][3] };
    *reinterpret_cast<float4*>(&obase[(size_t)(typ * 4 + ii) * DIMC + txp * 4]) = o;
  }
}

// ---------------------------------------------------------------------------
extern "C" void kernel_launch(void* const* d_in, const int* in_sizes, int n_in,
                              void* d_out, int out_size, void* d_ws, size_t ws_size,
                              hipStream_t stream) {
  (void)in_sizes; (void)n_in; (void)out_size; (void)ws_size;
  const float* x        = (const float*)d_in[0];
  const int*   labels   = (const int*)d_in[1];
  const float* scores   = (const float*)d_in[2];
  const int*   idx_last = (const int*)d_in[3];
  const float* Wq       = (const float*)d_in[4];
  const float* Wk       = (const float*)d_in[5];
  const float* Wv       = (const float*)d_in[6];
  const float* Wp       = (const float*)d_in[7];
  const float* betaL    = (const float*)d_in[8];
  float* out = (float*)d_out;

  char* w = (char*)d_ws;
  size_t off = 0;
  auto take = [&](size_t bytes) -> char* {
    char* p = w + off;
    off += (bytes + 255) & ~(size_t)255;
    return p;
  };
  float* qb    = (float*)take(33554432);   // q f32 (max 2*8192*512)
  float* kb    = (float*)take(33554432);   // k f32
  u16*   vbf   = (u16*)  take(16777216);   // v bf16
  float* xo    = (float*)take(33554432);   // xl (pooled x) / outp union
  u16*   attnA = (u16*)  take(16777216);   // lvl0 attn bf16
  u16*   attnB = (u16*)  take(33554432);   // lvl1 attn bf16
  u16*   wqhi  = (u16*)  take(524288);     // transposed+split weights
  u16*   wqlo  = (u16*)  take(524288);
  u16*   wkhi  = (u16*)  take(524288);
  u16*   wklo  = (u16*)  take(524288);
  u16*   wvhi  = (u16*)  take(524288);
  u16*   wphi  = (u16*)  take(524288);
  float* sl    = (float*)take(32768);
  int*   ll    = (int*)  take(32768);
  int*   keepb = (int*)  take(1024);
  // total ~171 MB

  const size_t wstride = (size_t)DIMC * DIMC;
  for (int lvl = 0; lvl < 3; ++lvl) {
    int scale = (lvl == 0) ? 4 : (lvl == 1) ? 2 : 1;
    int n_l = NTOK / scale;
    int ng  = n_l / GS;
    int M   = 2 * n_l;
    const float* xin; const int* lin; const float* sin_;
    if (scale > 1) {
      int tfeat = 2 * n_l * (DIMC / 4);
      pool_feat_kernel<<<(tfeat + 255) / 256, 256, 0, stream>>>(x, scores, xo, sl, NTOK, scale);
      pool_label_kernel<<<(2 * n_l + 255) / 256, 256, 0, stream>>>(labels, scores, ll, NTOK, scale);
      xin = xo; lin = ll; sin_ = sl;
    } else {
      xin = x; lin = labels; sin_ = scores;
    }
    keep_kernel<<<(2 * ng + 127) / 128, 128, 0, stream>>>(lin, sin_, keepb, 2 * ng);

    // weight transpose+split (tiny)
    wsplitT_kernel<<<256, 256, 0, stream>>>(Wq + lvl * wstride, wqhi, wqlo);
    wsplitT_kernel<<<256, 256, 0, stream>>>(Wk + lvl * wstride, wkhi, wklo);
    wsplitT_kernel<<<256, 256, 0, stream>>>(Wv + lvl * wstride, wvhi, nullptr);
    wsplitT_kernel<<<256, 256, 0, stream>>>(Wp + lvl * wstride, wphi, nullptr);

    dim3 gg(4, M / 128);
    mgemm_kernel<1, 0><<<gg, 256, 0, stream>>>(xin, wqhi, wqlo, qb, nullptr, nullptr, M, 0, 0);
    mgemm_kernel<1, 0><<<gg, 256, 0, stream>>>(xin, wkhi, wklo, kb, nullptr, nullptr, M, 0, 0);
    mgemm_kernel<0, 1><<<gg, 256, 0, stream>>>(xin, wvhi, nullptr, nullptr, vbf, nullptr, M, 0, 0);

    const u16* prev = (lvl == 0) ? nullptr : ((lvl == 1) ? attnA : attnB);
    u16* cur = (lvl == 0) ? attnA : ((lvl == 1) ? attnB : nullptr);
    attn_fused_kernel<<<2 * ng * 8, 512, 0, stream>>>(qb, kb, vbf, keepb, prev, cur,
                                                      betaL, xo, lvl, n_l, ng, ng / 2);

    if (lvl == 0)
      mgemm_kernel<0, 2><<<gg, 256, 0, stream>>>(xo, wphi, nullptr, out, nullptr, idx_last, M, scale, n_l);
    else
      mgemm_kernel<0, 3><<<gg, 256, 0, stream>>>(xo, wphi, nullptr, out, nullptr, idx_last, M, scale, n_l);
  }
}